// Round 3
// baseline (181666.089 us; speedup 1.0000x reference)
//
#include <hip/hip_runtime.h>
#include <hip/hip_bf16.h>
#include <stdint.h>
#include <stddef.h>

#define T_STEPS 262144
#define CHUNK   64
#define NCHUNK  (T_STEPS / CHUNK)

typedef float v2f __attribute__((ext_vector_type(2)));
typedef float v4f __attribute__((ext_vector_type(4)));

// packed dual-FMA: acc.lo += a.lo*b.lo ; acc.hi += a.hi*b.hi
#define PKFMA(acc, a, b) \
    asm("v_pk_fma_f32 %0, %1, %2, %0" : "+v"(acc) : "v"(a), "v"(b))

__device__ __forceinline__ v2f xload(const float* __restrict__ x, int g) {
    v2f v;
    v.x = (g     >= 0 && g     < T_STEPS * 8) ? x[g]     : 0.0f;
    v.y = (g + 1 >= 0 && g + 1 < T_STEPS * 8) ? x[g + 1] : 0.0f;
    return v;
}

// ---------------------------------------------------------------------------
// Sequential GRU scan. ONE workgroup, 256 threads = 4 waves (1 per SIMD).
// Lane (w,l): col = w*32 + (l&31) in [0,128); half = l>>5 selects rows
// [64*half, 64*half+64) of the 128-deep dots. Pair partner is lane^32.
// Per step: 96 pk_fma (recurrent) + 6 pk_fma (input proj), 4 shuffle-adds,
// gates computed redundantly in both halves (bitwise identical), ONE barrier.
// ---------------------------------------------------------------------------
__global__ __launch_bounds__(256, 1) void gru_scan(
    const float* __restrict__ xg,     // even_x, [T*8]
    const float* __restrict__ gk,     // gru_kernel [8][384]
    const float* __restrict__ gr,     // gru_rec_kernel [128][384]
    const float* __restrict__ gb,     // gru_bias [2][384]
    __hip_bfloat16* __restrict__ hsT) // out: h states, transposed [128][T]
{
    const int tid  = threadIdx.x;
    const int w    = tid >> 6;
    const int l    = tid & 63;
    const int col  = (w << 5) | (l & 31);   // 0..127
    const int half = l >> 5;                // 0 or 1
    const int r0   = half << 6;             // row base: 0 or 64

    __shared__ float hbuf[2][132];          // double-buffered h (pad to 132)
    __shared__ float xsh[2][CHUNK * 8];     // double-buffered x chunks

    // ---- recurrent weights: 3 gates x 32 row-pairs (this half's 64 rows) ----
    v2f wz[32], wrv[32], wn[32];
#pragma unroll
    for (int p = 0; p < 32; ++p) {
        const int r = r0 + 2 * p;
        wz[p].x  = gr[r * 384 + col];        wz[p].y  = gr[(r + 1) * 384 + col];
        wrv[p].x = gr[r * 384 + 128 + col];  wrv[p].y = gr[(r + 1) * 384 + 128 + col];
        wn[p].x  = gr[r * 384 + 256 + col];  wn[p].y  = gr[(r + 1) * 384 + 256 + col];
    }
    // ---- input-kernel weights: this half covers x rows [4*half, 4*half+4) ----
    v2f kz[2], kr[2], kn[2];
#pragma unroll
    for (int p = 0; p < 2; ++p) {
        const int r = 4 * half + 2 * p;
        kz[p].x = gk[r * 384 + col];         kz[p].y = gk[(r + 1) * 384 + col];
        kr[p].x = gk[r * 384 + 128 + col];   kr[p].y = gk[(r + 1) * 384 + 128 + col];
        kn[p].x = gk[r * 384 + 256 + col];   kn[p].y = gk[(r + 1) * 384 + 256 + col];
    }
    const float bz  = gb[col]       + gb[384 + col];   // z: b_i + b_r
    const float brc = gb[128 + col] + gb[512 + col];   // r: b_i + b_r
    const float bin = gb[256 + col];                   // n: input bias
    const float brn = gb[640 + col];                   // n: recurrent bias

    if (tid < 128) hbuf[0][tid] = 0.0f;                // h0 = 0
    // prefetch x chunk 0 (shift-by-one folded in: slot s holds even_x[t-1])
    v2f px = xload(xg, -8 + tid * 2);
    __syncthreads();

    for (int c = 0; c < NCHUNK; ++c) {
        const int cb = c & 1;
        // stage prefetched x (compiler inserts the vmcnt wait for px)
        xsh[cb][2 * tid]     = px.x;
        xsh[cb][2 * tid + 1] = px.y;
        if (c + 1 < NCHUNK) px = xload(xg, (c + 1) * (CHUNK * 8) - 8 + tid * 2);
        asm volatile("s_waitcnt lgkmcnt(0)" ::: "memory");
        __builtin_amdgcn_s_barrier();

#pragma unroll 1
        for (int s = 0; s < CHUNK; ++s) {
            const int t  = (c << 6) + s;
            const int rb = s & 1;              // read buffer (64 is even)
            const v4f* hq = ((const v4f*)&hbuf[rb][0]) + (half << 4);

            v2f az0 = {0.f, 0.f}, az1 = {0.f, 0.f};
            v2f ar0 = {0.f, 0.f}, ar1 = {0.f, 0.f};
            v2f an0 = {0.f, 0.f}, an1 = {0.f, 0.f};
#pragma unroll
            for (int m = 0; m < 16; ++m) {
                const v4f h4 = hq[m];          // broadcast LDS read, 4 h values
                v2f ha; ha.x = h4.x; ha.y = h4.y;
                v2f hb; hb.x = h4.z; hb.y = h4.w;
                PKFMA(az0, ha, wz[2 * m]);   PKFMA(az1, hb, wz[2 * m + 1]);
                PKFMA(ar0, ha, wrv[2 * m]);  PKFMA(ar1, hb, wrv[2 * m + 1]);
                PKFMA(an0, ha, wn[2 * m]);   PKFMA(an1, hb, wn[2 * m + 1]);
            }
            // input projection: this half's 4 x-features
            const v4f xq = ((const v4f*)&xsh[cb][s * 8])[half];
            v2f xa;  xa.x  = xq.x; xa.y  = xq.y;
            v2f xb2; xb2.x = xq.z; xb2.y = xq.w;
            PKFMA(az0, xa, kz[0]); PKFMA(az1, xb2, kz[1]);
            PKFMA(ar0, xa, kr[0]); PKFMA(ar1, xb2, kr[1]);
            v2f gxn2 = {0.f, 0.f};
            PKFMA(gxn2, xa, kn[0]); PKFMA(gxn2, xb2, kn[1]);

            const float hold = hbuf[rb][col];

            float pz  = (az0.x + az0.y) + (az1.x + az1.y);
            float pr  = (ar0.x + ar0.y) + (ar1.x + ar1.y);
            float pn  = (an0.x + an0.y) + (an1.x + an1.y);
            float pxn = gxn2.x + gxn2.y;
            // combine pair halves (partner holds the other 64 rows / 4 feats)
            pz  += __shfl_xor(pz, 32);
            pr  += __shfl_xor(pr, 32);
            pn  += __shfl_xor(pn, 32);
            pxn += __shfl_xor(pxn, 32);

            const float zarg = pz + bz;
            const float rarg = pr + brc;
            const float hn   = pn + brn;         // recurrent n (gets gated by r)
            const float xh   = pxn + bin;        // input n
            const float z  = 1.0f / (1.0f + __expf(-zarg));
            const float rg = 1.0f / (1.0f + __expf(-rarg));
            const float hh = 1.0f - 2.0f / (1.0f + __expf(2.0f * fmaf(rg, hn, xh)));
            const float hnew = fmaf(z, hold - hh, hh);   // z*h + (1-z)*hh

            if (half == 0) {
                hbuf[rb ^ 1][col] = hnew;                 // next step's h
            } else {
                // fire-and-forget bf16 store, transposed; L2 merges over t
                hsT[(size_t)col * T_STEPS + t] = __float2bfloat16(hnew);
            }
            // LDS-only wait: do NOT drain vmcnt (stores stay in flight)
            asm volatile("s_waitcnt lgkmcnt(0)" ::: "memory");
            __builtin_amdgcn_s_barrier();
        }
    }
}

// ---------------------------------------------------------------------------
// Dense tail: y[t][:] = hs[t][:] @ dk + db. Thread per t, W staged in LDS,
// float4 broadcast reads, coalesced bf16 reads from transposed hsT.
// ---------------------------------------------------------------------------
__global__ __launch_bounds__(256) void dense_out(
    const __hip_bfloat16* __restrict__ hsT,  // [128][T]
    const float* __restrict__ dk,            // [128][96]
    const float* __restrict__ db,            // [96]
    float* __restrict__ out)                 // [T][96]
{
    __shared__ float wl[128 * 96];
    for (int k = threadIdx.x; k < 128 * 96; k += 256) wl[k] = dk[k];
    __syncthreads();

    const int t = blockIdx.x * 256 + threadIdx.x;
    v4f acc[24];
#pragma unroll
    for (int o = 0; o < 24; ++o) acc[o] = ((const v4f*)db)[o];

#pragma unroll 4
    for (int i = 0; i < 128; ++i) {
        const float h = __bfloat162float(hsT[(size_t)i * T_STEPS + t]);
        const v4f* wp = (const v4f*)&wl[i * 96];
#pragma unroll
        for (int o = 0; o < 24; ++o) {
            const v4f wv = wp[o];
            acc[o].x = fmaf(h, wv.x, acc[o].x);
            acc[o].y = fmaf(h, wv.y, acc[o].y);
            acc[o].z = fmaf(h, wv.z, acc[o].z);
            acc[o].w = fmaf(h, wv.w, acc[o].w);
        }
    }
    v4f* op = (v4f*)(out + (size_t)t * 96);
#pragma unroll
    for (int o = 0; o < 24; ++o) op[o] = acc[o];
}

// ---------------------------------------------------------------------------
extern "C" void kernel_launch(void* const* d_in, const int* in_sizes, int n_in,
                              void* d_out, int out_size, void* d_ws, size_t ws_size,
                              hipStream_t stream) {
    const float* even_x = (const float*)d_in[0];
    const float* gk     = (const float*)d_in[1];
    const float* gr     = (const float*)d_in[2];
    const float* gb     = (const float*)d_in[3];
    const float* dk     = (const float*)d_in[4];
    const float* db     = (const float*)d_in[5];
    float* out          = (float*)d_out;

    // hsT needs 128*T*2 = 64 MiB. Guard against an undersized workspace:
    // fall back to d_out (valid 96 MiB) — output then fails absmax (tripwire)
    // instead of faulting the GPU with OOB writes.
    const size_t need = (size_t)128 * T_STEPS * sizeof(__hip_bfloat16);
    __hip_bfloat16* hsT = (ws_size >= need) ? (__hip_bfloat16*)d_ws
                                            : (__hip_bfloat16*)d_out;

    gru_scan<<<1, 256, 0, stream>>>(even_x, gk, gr, gb, hsT);
    dense_out<<<T_STEPS / 256, 256, 0, stream>>>(hsT, dk, db, out);
}